// Round 7
// baseline (7139.302 us; speedup 1.0000x reference)
//
#include <hip/hip_runtime.h>
#include <stdint.h>

#define NB    16   // batches
#define WPB   16   // workgroups per batch
#define NTHR  512  // threads per workgroup (8 waves)
#define NWAVE 8
#define PPT   16   // points per thread
#define SLOTS_PER_BATCH (WPB * NWAVE)          // 128 per-wave slots
#define LDS_BYTES (3 * PPT * NTHR * 4)         // 96 KiB coord planes

// JAX Threefry-2x32 (20 rounds), exact.
__device__ __forceinline__ void tf2x32(uint32_t k0, uint32_t k1,
                                       uint32_t x0, uint32_t x1,
                                       uint32_t &y0, uint32_t &y1) {
  uint32_t ks2 = k0 ^ k1 ^ 0x1BD11BDAu;
  uint32_t v0 = x0 + k0, v1 = x1 + k1;
#define TFR(r) { v0 += v1; v1 = (v1 << (r)) | (v1 >> (32 - (r))); v1 ^= v0; }
  TFR(13) TFR(15) TFR(26) TFR(6)   v0 += k1;  v1 += ks2 + 1u;
  TFR(17) TFR(29) TFR(16) TFR(24)  v0 += ks2; v1 += k0 + 2u;
  TFR(13) TFR(15) TFR(26) TFR(6)   v0 += k0;  v1 += k1 + 3u;
  TFR(17) TFR(29) TFR(16) TFR(24)  v0 += k1;  v1 += ks2 + 4u;
  TFR(13) TFR(15) TFR(26) TFR(6)   v0 += ks2; v1 += k0 + 5u;
#undef TFR
  y0 = v0; y1 = v1;
}

// R7: barrier-free per-wave sync. 128 slots per (parity,batch); slot
// [tag:13 | dist_bits:32 | inv_idx:19] written by each wave's lane 0; every
// wave polls all 128 (2 u64/lane), reduces, gathers centroid itself.
// Parity double-buffer: publish for iter i is control-dependent on the
// poll of iter i-1 completing, so a wave can never overwrite a slot that
// any other wave still needs (2 iters ahead shares parity but requires
// ALL waves to have exited the intervening poll first).
__global__ __launch_bounds__(NTHR, 4)
void FPSampler_42099269435595_kernel(const float* __restrict__ xyz,
                                     const int* __restrict__ npoint_ptr,
                                     float* __restrict__ out,
                                     unsigned long long* __restrict__ slots,
                                     int N) {
#pragma clang fp contract(off)
  extern __shared__ float smem[];
  const int blk  = blockIdx.x;
  const int b    = blk >> 4;          // batch
  const int w    = blk & (WPB - 1);   // wg within batch
  const int tid  = threadIdx.x;
  const int wave = tid >> 6;
  const int lane = tid & 63;
  const int npoint = npoint_ptr[0];

  const float* __restrict__ xb = xyz + (size_t)b * N * 3;
  const int p0 = w * (N / WPB) + tid;   // strided points (R1 layout)

  // Coord planes [plane][k][tid]: per-lane stride-1 -> conflict-free b32
  // reads. volatile: no barriers remain in the loop, so without it LICM
  // would hoist the loop-invariant ds_reads into 48 VGPRs (the R1-R4 spill
  // fight). Each thread reads only what it wrote -> no barrier needed.
  volatile float* lx = smem;
  volatile float* ly = smem + PPT * NTHR;
  volatile float* lz = smem + 2 * PPT * NTHR;

  float dist[PPT];
#pragma unroll
  for (int k = 0; k < PPT; ++k) {
    size_t p = (size_t)(p0 + k * NTHR);
    lx[k * NTHR + tid] = xb[3 * p + 0];
    ly[k * NTHR + tid] = xb[3 * p + 1];
    lz[k * NTHR + tid] = xb[3 * p + 2];
    dist[k] = 1e10f;
  }

  // start = randint(fold_in(key(0),1),(16,),0,2^17)  (threefry, partitionable)
  uint32_t fk0, fk1, s0, s1, r0, r1;
  tf2x32(0u, 0u, 0u, 1u, fk0, fk1);          // fold_in(key(0), 1)
  tf2x32(fk0, fk1, 0u, 1u, s0, s1);          // split(key)[1]
  tf2x32(s0, s1, 0u, (uint32_t)b, r0, r1);   // random_bits element b
  uint32_t far = (r0 ^ r1) & 0x1FFFFu;       // % 131072 (span = 2^17)

  // centroid gather via scalar path (far is wave-uniform)
  int sfar = __builtin_amdgcn_readfirstlane((int)far);
  float cx = xb[3 * (size_t)sfar + 0];
  float cy = xb[3 * (size_t)sfar + 1];
  float cz = xb[3 * (size_t)sfar + 2];

  float* out_xyz = out;                           // (B, npoint, 3)
  float* out_idx = out + (size_t)NB * npoint * 3; // (B, npoint) as float

  for (int i = 0; i < npoint; ++i) {
    if (w == 0 && tid == NTHR - 1) {
      size_t o = (size_t)b * npoint + i;
      out_xyz[3 * o + 0] = cx;
      out_xyz[3 * o + 1] = cy;
      out_xyz[3 * o + 2] = cz;
      out_idx[o] = (float)far;     // scan emits farthest BEFORE update
    }
    if (i == npoint - 1) break;

    // ---- distance update + per-thread argmax (LDS coords, VGPR dist) ----
    float best = -1.0f;
    uint32_t bidx = 0;
#pragma unroll
    for (int k = 0; k < PPT; ++k) {
      float xk = lx[k * NTHR + tid];
      float yk = ly[k * NTHR + tid];
      float zk = lz[k * NTHR + tid];
      float dx = xk - cx, dy = yk - cy, dz = zk - cz;
      float d = (dx * dx + dy * dy) + dz * dz;  // match XLA: no FMA contract
      float nd = fminf(dist[k], d);
      dist[k] = nd;
      if (nd > best) { best = nd; bidx = (uint32_t)(p0 + k * NTHR); }
    }

    // ---- wave reduce (6 shfl levels), then lane 0 publishes wave-max ----
    const uint32_t tag = (uint32_t)(i + 1);
    unsigned long long pk =
        ((unsigned long long)tag << 51) |
        ((unsigned long long)__float_as_uint(best) << 19) |
        (unsigned long long)(0x7FFFFu - bidx);
#pragma unroll
    for (int off = 32; off >= 1; off >>= 1) {
      unsigned long long o = __shfl_xor(pk, off);
      if (o > pk) pk = o;
    }
    unsigned long long* base =
        slots + (size_t)((i & 1) * NB + b) * SLOTS_PER_BATCH;
    if (lane == 0)
      __hip_atomic_store(base + w * NWAVE + wave, pk, __ATOMIC_RELAXED,
                         __HIP_MEMORY_SCOPE_AGENT);

    // ---- every wave polls all 128 slots (2 u64 per lane) ----
    unsigned long long v0, v1;
    do {
      v0 = __hip_atomic_load(base + lane, __ATOMIC_RELAXED,
                             __HIP_MEMORY_SCOPE_AGENT);
      v1 = __hip_atomic_load(base + 64 + lane, __ATOMIC_RELAXED,
                             __HIP_MEMORY_SCOPE_AGENT);
    } while (__any(((uint32_t)(v0 >> 51) != tag) |
                   ((uint32_t)(v1 >> 51) != tag)));

    // ---- global winner: 128 -> 64 -> shfl tree; keys carry idx ----
    unsigned long long gk = (v0 > v1) ? v0 : v1;
#pragma unroll
    for (int off = 32; off >= 1; off >>= 1) {
      unsigned long long o = __shfl_xor(gk, off);
      if (o > gk) gk = o;
    }
    far = 0x7FFFFu - (uint32_t)(gk & 0x7FFFFu);
    sfar = __builtin_amdgcn_readfirstlane((int)far);
    cx = xb[3 * (size_t)sfar + 0];
    cy = xb[3 * (size_t)sfar + 1];
    cz = xb[3 * (size_t)sfar + 2];
  }
}

extern "C" void kernel_launch(void* const* d_in, const int* in_sizes, int n_in,
                              void* d_out, int out_size, void* d_ws, size_t ws_size,
                              hipStream_t stream) {
  const float* xyz = (const float*)d_in[0];
  const int* npoint = (const int*)d_in[1];
  int N = in_sizes[0] / (NB * 3);  // 131072

  // allow >64KB dynamic LDS (96 KiB); idempotent, capture-safe
  hipFuncSetAttribute((const void*)FPSampler_42099269435595_kernel,
                      hipFuncAttributeMaxDynamicSharedMemorySize, LDS_BYTES);

  // zero slot words (2 parities x 16 batches x 128 slots x 8 B = 32 KiB);
  // tags start at 1 so 0 never matches.
  hipMemsetAsync(d_ws, 0,
                 (size_t)2 * NB * SLOTS_PER_BATCH * sizeof(unsigned long long),
                 stream);
  FPSampler_42099269435595_kernel<<<NB * WPB, NTHR, LDS_BYTES, stream>>>(
      xyz, npoint, (float*)d_out, (unsigned long long*)d_ws, N);
}